// Round 1
// baseline (21155.284 us; speedup 1.0000x reference)
//
#include <hip/hip_runtime.h>

typedef _Float16 f16;
typedef _Float16 f16x8 __attribute__((ext_vector_type(8)));
typedef float f32x4 __attribute__((ext_vector_type(4)));

#define T_STEPS 1024
#define BATCH 128
#define HID 512
#define VOC 65
#define DRING 8
#define NLWG 192              // 3 layers * 32 dim-slices * 2 batch-halves
#define NPWG 20               // 4 b-tiles * 5 v-tiles
#define READY_STRIDE 1088

// workspace layout (bytes)
#define OFF_READY 0
#define OFF_HRING 32768
#define HRING_BYTES (3*DRING*BATCH*HID*2)            // 3,145,728
#define OFF_WPACK (OFF_HRING + HRING_BYTES)          // 3,178,496
#define WPACK_BYTES (3*32*64*1024*2)                 // 12,582,912
#define OFF_WOUT (OFF_WPACK + WPACK_BYTES)           // 15,761,408
#define WOUT_BYTES (5*16*512*2)                      // 81,920
#define OFF_EMB (OFF_WOUT + WOUT_BYTES)              // 15,843,328

__device__ __forceinline__ float sigmoidf_(float x){ return 1.0f/(1.0f+__expf(-x)); }
__device__ __forceinline__ float tanhf_(float x){ return 1.0f - 2.0f/(__expf(2.0f*x)+1.0f); }

// Pack weights: per (layer l, slice g of 16 dims): 64 rows x 1024 k fp16.
// rows 0-15: r (W rows d), 16-31: z (512+d), 32-47: n hi (1024+d), 48-63: n lo*2048.
// k<512 -> w_ih, k>=512 -> w_hh. Also w_out -> fp16 [5 vtiles][16][512], emb -> fp16.
__global__ void convert_kernel(const float* __restrict__ emb, const float* __restrict__ w_ih,
                               const float* __restrict__ w_hh, const float* __restrict__ w_out,
                               char* __restrict__ ws) {
  f16* wpack = (f16*)(ws + OFF_WPACK);
  f16* wout  = (f16*)(ws + OFF_WOUT);
  f16* embh  = (f16*)(ws + OFF_EMB);
  const long NW = 3L*32*64*1024;                      // 6,291,456 (2^21 per layer)
  const long TOT = NW + 5*16*512 + VOC*HID;
  for (long e = (long)blockIdx.x*blockDim.x + threadIdx.x; e < TOT; e += (long)gridDim.x*blockDim.x) {
    if (e < NW) {
      int l = (int)(e >> 21);
      int rem = (int)(e & 2097151);
      int g = rem >> 16;
      int r2 = rem & 65535;
      int R = r2 >> 10, k = r2 & 1023;
      int d = g*16 + (R & 15), gt = R >> 4;
      int row = (gt==0) ? d : (gt==1) ? (512+d) : (1024+d);
      float f = (k < 512) ? w_ih[((size_t)(l*1536+row)<<9) + k]
                          : w_hh[((size_t)(l*1536+row)<<9) + (k-512)];
      f16 h;
      if (gt < 3) h = (f16)f;
      else { f16 hi = (f16)f; h = (f16)((f - (float)hi)*2048.0f); }
      wpack[e] = h;
    } else if (e < NW + 5*16*512) {
      int e2 = (int)(e - NW); int vt = e2 >> 13; int r2 = e2 & 8191; int n = r2 >> 9, k = r2 & 511;
      int v = vt*16 + n;
      wout[e2] = (v < VOC) ? (f16)w_out[((size_t)v<<9)+k] : (f16)0.0f;
    } else {
      int e2 = (int)(e - NW - 5*16*512);
      embh[e2] = (f16)emb[e2];
    }
  }
}

// Persistent kernel. 212 WGs x 256 threads.
// wg<192: layer WG: l=wg/64, g=(wg%64)/2 (dim slice), bh=wg%2 (batch half, M=64).
//   waves = 4 m-tiles of 16. Per step: fused [x;h] GEMM k=1024 via 16x16x32_f16 MFMA.
//   W r/z frags register-resident; n-hi/n-lo from LDS. A-frags direct global->VGPR.
// wg in [192,212): projection: bt=p/5 (32 b), vt=p%5 (16 v rows), waves 0/1 compute.
__global__ void __launch_bounds__(256) rnn_kernel(const int* __restrict__ xseq,
                           const float* __restrict__ bias, const float* __restrict__ bias_n,
                           const float* __restrict__ b_out, float* __restrict__ out,
                           char* __restrict__ ws) {
  unsigned* ready = (unsigned*)(ws + OFF_READY);      // [4][READY_STRIDE]
  f16* hring = (f16*)(ws + OFF_HRING);                // [3][8][128][512]
  const int wg = blockIdx.x;
  const int tid = threadIdx.x;
  const int lane = tid & 63, wave = tid >> 6;
  const int quad = lane >> 4, ko = quad*8, nlane = lane & 15;

  if (wg < NLWG) {
    const int l = wg / 64, r = wg % 64, g = r >> 1, bh = r & 1;
    __shared__ f16 wlds[64][1032];                    // 132,096 B -> 1 WG/CU
    {
      const f16* src = (const f16*)(ws + OFF_WPACK) + ((size_t)(l*32+g) << 16);
      for (int i = tid; i < 8192; i += 256) {
        int row = i >> 7, col = (i & 127) << 3;
        *(f16x8*)&wlds[row][col] = *(const f16x8*)(src + ((size_t)i << 3));
      }
    }
    const int j = g*16 + nlane;                       // this lane's output dim
    const float br  = bias[l*1536 + j];
    const float bz  = bias[l*1536 + 512 + j];
    const float bin = bias[l*1536 + 1024 + j];
    const float bn  = bias_n[l*512 + j];
    const int bm = bh*64 + wave*16 + nlane;           // A-operand batch row
    unsigned* rdy_self = ready + l*READY_STRIDE;
    unsigned* rdy_prev = ready + (l-1)*READY_STRIDE;  // only used if l>0
    unsigned* rdy_next = ready + (l+1)*READY_STRIDE;  // l==2 -> proj counters
    const unsigned next_target = (l == 2) ? NPWG : 64;
    __syncthreads();
    // register-resident W fragments for r and z gates (256 VGPRs)
    f16x8 wr[32], wz[32];
#pragma unroll
    for (int kc = 0; kc < 32; ++kc) {
      wr[kc] = *(const f16x8*)&wlds[nlane][kc*32 + ko];
      wz[kc] = *(const f16x8*)&wlds[16 + nlane][kc*32 + ko];
    }
    const f16* embh = (const f16*)(ws + OFF_EMB);

    for (int t = 0; t < T_STEPS; ++t) {
      if (tid == 0) {
        if (l > 0)
          while (__hip_atomic_load(rdy_prev + t, __ATOMIC_RELAXED, __HIP_MEMORY_SCOPE_AGENT) < 64u)
            __builtin_amdgcn_s_sleep(1);
        if (t >= 1)
          while (__hip_atomic_load(rdy_self + (t-1), __ATOMIC_RELAXED, __HIP_MEMORY_SCOPE_AGENT) < 64u)
            __builtin_amdgcn_s_sleep(1);
        if (t >= DRING)
          while (__hip_atomic_load(rdy_next + (t-DRING), __ATOMIC_RELAXED, __HIP_MEMORY_SCOPE_AGENT) < next_target)
            __builtin_amdgcn_s_sleep(1);
        __threadfence();                              // acquire: invalidate for fresh h reads
      }
      __syncthreads();

      const f16* xrow;
      if (l == 0) {
        int idx = xseq[bm*T_STEPS + t];
        xrow = embh + (size_t)idx*HID;
      } else {
        xrow = hring + (((size_t)((l-1)*DRING + (t & 7))*BATCH + bm))*HID;
      }
      const f16* hrow = hring + (((size_t)(l*DRING + ((t+7) & 7))*BATCH + bm))*HID;

      f32x4 ar{0,0,0,0}, az{0,0,0,0}, anxh{0,0,0,0}, anxl{0,0,0,0}, anhh{0,0,0,0}, anhl{0,0,0,0};
#pragma unroll
      for (int kc = 0; kc < 32; ++kc) {
        const f16* s = (kc < 16) ? (xrow + kc*32) : (hrow + (kc-16)*32);
        f16x8 a = *(const f16x8*)(s + ko);
        f16x8 wnh = *(const f16x8*)&wlds[32 + nlane][kc*32 + ko];
        f16x8 wnl = *(const f16x8*)&wlds[48 + nlane][kc*32 + ko];
        ar = __builtin_amdgcn_mfma_f32_16x16x32_f16(a, wr[kc], ar, 0, 0, 0);
        az = __builtin_amdgcn_mfma_f32_16x16x32_f16(a, wz[kc], az, 0, 0, 0);
        if (kc < 16) {
          anxh = __builtin_amdgcn_mfma_f32_16x16x32_f16(a, wnh, anxh, 0, 0, 0);
          anxl = __builtin_amdgcn_mfma_f32_16x16x32_f16(a, wnl, anxl, 0, 0, 0);
        } else {
          anhh = __builtin_amdgcn_mfma_f32_16x16x32_f16(a, wnh, anhh, 0, 0, 0);
          anhl = __builtin_amdgcn_mfma_f32_16x16x32_f16(a, wnl, anhl, 0, 0, 0);
        }
      }
      // epilogue: D layout col(lane&15)=dim, row(quad*4+i)=batch
      f16* hw = hring + ((size_t)(l*DRING + (t & 7))*BATCH)*HID;
      const f16* hp_base = hring + ((size_t)(l*DRING + ((t+7) & 7))*BATCH)*HID;
#pragma unroll
      for (int i = 0; i < 4; ++i) {
        int bidx = bh*64 + wave*16 + quad*4 + i;
        float rr = sigmoidf_(ar[i] + br);
        float zz = sigmoidf_(az[i] + bz);
        float hn = anhh[i] + anhl[i]*(1.0f/2048.0f) + bn;
        float nn = tanhf_(anxh[i] + anxl[i]*(1.0f/2048.0f) + bin + rr*hn);
        float hp = (float)hp_base[(size_t)bidx*HID + j];
        float hv = nn + zz*(hp - nn);
        hw[(size_t)bidx*HID + j] = (f16)hv;
      }
      __syncthreads();
      if (tid == 0) { __threadfence(); atomicAdd(rdy_self + t, 1u); }
    }
  } else if (wg < NLWG + NPWG) {
    const int p = wg - NLWG, bt = p / 5, vt = p % 5;
    __shared__ f16 wolds[16][520];
    {
      const f16* src = (const f16*)(ws + OFF_WOUT) + vt*8192;
      for (int i = tid; i < 1024; i += 256) {
        int row = i >> 6, col = (i & 63) << 3;
        *(f16x8*)&wolds[row][col] = *(const f16x8*)(src + (i << 3));
      }
    }
    const int v = vt*16 + nlane;
    const float bo = (v < VOC) ? b_out[v] : 0.0f;
    unsigned* rdy2 = ready + 2*READY_STRIDE;
    unsigned* rdyP = ready + 3*READY_STRIDE;
    __syncthreads();
    for (int t = 0; t < T_STEPS; ++t) {
      if (tid == 0) {
        while (__hip_atomic_load(rdy2 + t, __ATOMIC_RELAXED, __HIP_MEMORY_SCOPE_AGENT) < 64u)
          __builtin_amdgcn_s_sleep(1);
        __threadfence();
      }
      __syncthreads();
      if (wave < 2) {
        const int bmb = bt*32 + wave*16;
        const f16* hrow = hring + (((size_t)(2*DRING + (t & 7))*BATCH + bmb + nlane))*HID;
        f32x4 acc{0,0,0,0};
#pragma unroll
        for (int kc = 0; kc < 16; ++kc) {
          f16x8 a = *(const f16x8*)(hrow + kc*32 + ko);
          f16x8 w = *(const f16x8*)&wolds[nlane][kc*32 + ko];
          acc = __builtin_amdgcn_mfma_f32_16x16x32_f16(a, w, acc, 0, 0, 0);
        }
        if (v < VOC) {
#pragma unroll
          for (int i = 0; i < 4; ++i) {
            int bidx = bmb + quad*4 + i;
            out[((size_t)bidx*T_STEPS + t)*VOC + v] = acc[i] + bo;
          }
        }
      }
      __syncthreads();
      if (tid == 0) atomicAdd(rdyP + t, 1u);
    }
  }
}

extern "C" void kernel_launch(void* const* d_in, const int* in_sizes, int n_in,
                              void* d_out, int out_size, void* d_ws, size_t ws_size,
                              hipStream_t stream) {
  const int*   xseq  = (const int*)d_in[0];
  const float* emb   = (const float*)d_in[1];
  const float* w_ih  = (const float*)d_in[2];
  const float* w_hh  = (const float*)d_in[3];
  const float* b     = (const float*)d_in[4];
  const float* b_n   = (const float*)d_in[5];
  const float* w_out = (const float*)d_in[6];
  const float* b_out = (const float*)d_in[7];
  char* ws = (char*)d_ws;

  // zero flag counters + h ring (h[-1] = 0 initial state); re-done every call
  hipMemsetAsync(d_ws, 0, OFF_HRING + HRING_BYTES, stream);
  hipLaunchKernelGGL(convert_kernel, dim3(4096), dim3(256), 0, stream,
                     emb, w_ih, w_hh, w_out, ws);
  hipLaunchKernelGGL(rnn_kernel, dim3(NLWG + NPWG), dim3(256), 0, stream,
                     xseq, b, b_n, b_out, (float*)d_out, ws);
}

// Round 2
// 10119.232 us; speedup vs baseline: 2.0906x; 2.0906x over previous
//
#include <hip/hip_runtime.h>

typedef _Float16 f16;
typedef _Float16 f16x8 __attribute__((ext_vector_type(8)));
typedef float f32x4 __attribute__((ext_vector_type(4)));

#define T_STEPS 1024
#define BATCH 128
#define HID 512
#define VOC 65
#define DRING 8
#define NLWG 192              // 3 layers * 32 dim-slices * 2 batch-halves
#define NPWG 20               // 4 b-tiles * 5 v-tiles
#define NEG_INF_I ((int)0x80000000)

// workspace layout (bytes)
#define OFF_READY 0           // int flags[4][64]: [l][bh*32+g], [3][p] for proj
#define OFF_HRING 32768
#define HRING_BYTES (3*DRING*BATCH*HID*2)            // 3,145,728
#define OFF_WPACK (OFF_HRING + HRING_BYTES)          // 3,178,496
#define WPACK_BYTES (3*32*65536*2)                   // 12,582,912
#define OFF_WOUT (OFF_WPACK + WPACK_BYTES)           // 15,761,408
#define WOUT_BYTES (5*16*512*2)                      // 81,920
#define OFF_EMB (OFF_WOUT + WOUT_BYTES)              // 15,843,328

__device__ __forceinline__ float sigmoidf_(float x){ return 1.0f/(1.0f+__expf(-x)); }
__device__ __forceinline__ float tanhf_(float x){ return 1.0f - 2.0f/(__expf(2.0f*x)+1.0f); }

// coherent 16B load: bypass L1+L2, read from coherence point (fresh cross-XCD data)
__device__ __forceinline__ f16x8 ld16_sc(const f16* p) {
  f16x8 r;
  asm volatile("global_load_dwordx4 %0, %1, off sc0 sc1" : "=v"(r) : "v"(p) : "memory");
  return r;
}

// Pack weights FRAG-MAJOR: per (layer l, slice g): 4 gate-tiles (r, z, n-hi, n-lo*2048)
// x 32 kc x [64 lanes x 8 f16] so a wave's ds_read_b128 is conflict-free.
// lane -> B-frag element: n = lane&15, k = kc*32 + (lane>>4)*8 + j.
__global__ void convert_kernel(const float* __restrict__ emb, const float* __restrict__ w_ih,
                               const float* __restrict__ w_hh, const float* __restrict__ w_out,
                               char* __restrict__ ws) {
  f16* wpack = (f16*)(ws + OFF_WPACK);
  f16* wout  = (f16*)(ws + OFF_WOUT);
  f16* embh  = (f16*)(ws + OFF_EMB);
  const int NW = 3*32*65536;                          // 6,291,456 (2^21 per layer)
  const int TOT = NW + 40960 + VOC*HID;
  for (int e = blockIdx.x*blockDim.x + threadIdx.x; e < TOT; e += gridDim.x*blockDim.x) {
    if (e < NW) {
      int l = e >> 21, rem = e & 0x1FFFFF;
      int g = rem >> 16, idx = rem & 0xFFFF;
      int gt = idx >> 14, kc = (idx >> 9) & 31, lane = (idx >> 3) & 63, jj = idx & 7;
      int n = lane & 15, q = lane >> 4;
      int k = kc*32 + q*8 + jj, d = g*16 + n;
      int row = (gt==0) ? d : (gt==1) ? 512+d : 1024+d;
      float f = (k < 512) ? w_ih[((size_t)(l*1536+row)<<9) + k]
                          : w_hh[((size_t)(l*1536+row)<<9) + (k-512)];
      f16 h;
      if (gt < 3) h = (f16)f;
      else { f16 hi = (f16)f; h = (f16)((f - (float)hi)*2048.0f); }
      wpack[e] = h;
    } else if (e < NW + 40960) {
      int idx = e - NW;
      int vt = idx >> 13, r2 = idx & 8191;
      int kc = r2 >> 9, lane = (r2 >> 3) & 63, jj = r2 & 7;
      int n = lane & 15, q = lane >> 4;
      int v = vt*16 + n, k = kc*32 + q*8 + jj;
      wout[idx] = (v < VOC) ? (f16)w_out[((size_t)v<<9) + k] : (f16)0.0f;
    } else {
      int idx = e - NW - 40960;
      embh[idx] = (f16)emb[idx];
    }
  }
}

// Persistent kernel, 212 WGs x 256 threads. No fences, no atomic RMWs:
// producers do sc1 write-through h stores + vmcnt(0) + per-producer flag stores;
// consumers poll 32 flags in parallel (1 lane each) and read h with sc0-sc1 loads.
__global__ void __launch_bounds__(256) rnn_kernel(const int* __restrict__ xseq,
                           const float* __restrict__ bias, const float* __restrict__ bias_n,
                           const float* __restrict__ b_out, float* __restrict__ out,
                           char* __restrict__ ws) {
  int* F = (int*)(ws + OFF_READY);
  f16* hring = (f16*)(ws + OFF_HRING);                // [3][8][128][512]
  const int wg = blockIdx.x;
  const int tid = threadIdx.x;
  const int lane = tid & 63, wv = tid >> 6;
  const int quad = lane >> 4, ko = quad*8, nlane = lane & 15;

  if (wg < NLWG) {
    const int l = wg / 64, r = wg % 64, g = r >> 1, bh = r & 1;
    __shared__ __align__(16) f16 wlds[65536];         // 131,072 B -> 1 WG/CU
    {
      const f16x8* src = (const f16x8*)((const f16*)(ws + OFF_WPACK) + ((size_t)(l*32+g) << 16));
      f16x8* dst = (f16x8*)wlds;
      for (int i = tid; i < 8192; i += 256) dst[i] = src[i];
    }
    const int j = g*16 + nlane;
    const float br  = bias[l*1536 + j];
    const float bz  = bias[l*1536 + 512 + j];
    const float bin = bias[l*1536 + 1024 + j];
    const float bn  = bias_n[l*512 + j];
    const int bm = bh*64 + wv*16 + nlane;             // A-operand batch row

    // per-lane poll assignment: wave0 = self(>=t) + prev(>=t+1); wave1 = downstream(>=t-7)
    const int* pollp = F; int padd = 0; int pact = 0;
    if (wv == 0) {
      if (lane < 32)      { pollp = F + l*64 + bh*32 + lane;        padd = 0;  pact = 1; }
      else if (l > 0)     { pollp = F + (l-1)*64 + bh*32 + lane-32; padd = 1;  pact = 1; }
    } else if (wv == 1) {
      if (l < 2) { if (lane < 32) { pollp = F + (l+1)*64 + bh*32 + lane; padd = -(DRING-1); pact = 1; } }
      else       { if (lane < 10) { pollp = F + 3*64 + bh*10 + lane;     padd = -(DRING-1); pact = 1; } }
    }
    __syncthreads();
    // register-resident (AGPR-parked) B-frags for r and z gates; conflict-free reads
    f16x8 wr[32], wz[32];
#pragma unroll
    for (int kc = 0; kc < 32; ++kc) {
      wr[kc] = *(const f16x8*)(wlds + (((0*32 + kc)*64 + lane) << 3));
      wz[kc] = *(const f16x8*)(wlds + (((1*32 + kc)*64 + lane) << 3));
    }
    const f16* embh = (const f16*)(ws + OFF_EMB);

    for (int t = 0; t < T_STEPS; ++t) {
      if (wv < 2) {
        const int tgt = pact ? (t + padd) : NEG_INF_I;
        int spins = 0;
        while (1) {
          int v = __hip_atomic_load(pollp, __ATOMIC_RELAXED, __HIP_MEMORY_SCOPE_AGENT);
          if (__all(v >= tgt)) break;
          if (++spins > (1 << 21)) break;             // hang-safety: fail visibly, not forever
          __builtin_amdgcn_s_sleep(2);
        }
      }
      __syncthreads();

      const int slot_w = t & (DRING-1), slot_r = (t + DRING - 1) & (DRING-1);
      f16x8 afr[32];
      if (l == 0) {
        int idx = xseq[bm*T_STEPS + t];
        const f16* xr = embh + (size_t)idx*HID + ko;  // immutable: plain cached loads
#pragma unroll
        for (int kc = 0; kc < 16; ++kc) afr[kc] = *(const f16x8*)(xr + kc*32);
      } else {
        const f16* xr = hring + ((size_t)((l-1)*DRING + slot_w)*BATCH + bm)*HID + ko;
#pragma unroll
        for (int kc = 0; kc < 16; ++kc) afr[kc] = ld16_sc(xr + kc*32);
      }
      {
        const f16* hrk = hring + ((size_t)(l*DRING + slot_r)*BATCH + bm)*HID + ko;
#pragma unroll
        for (int kc = 0; kc < 16; ++kc) afr[16 + kc] = ld16_sc(hrk + kc*32);
      }
      unsigned hpu[4];
      {
        const unsigned short* hpb = (const unsigned short*)(hring + ((size_t)(l*DRING + slot_r)*BATCH)*HID) + j;
#pragma unroll
        for (int i = 0; i < 4; ++i) {
          const unsigned short* p = hpb + (size_t)(bh*64 + wv*16 + quad*4 + i)*HID;
          asm volatile("global_load_ushort %0, %1, off sc0 sc1" : "=v"(hpu[i]) : "v"(p) : "memory");
        }
      }
      asm volatile("s_waitcnt vmcnt(0)" ::: "memory");
      // launder: pin consumers after the waitcnt (asm results otherwise look "ready" early)
      if (l > 0) {
#pragma unroll
        for (int kc = 0; kc < 16; ++kc) asm volatile("" : "+v"(afr[kc]));
      }
#pragma unroll
      for (int kc = 0; kc < 16; ++kc) asm volatile("" : "+v"(afr[16 + kc]));
#pragma unroll
      for (int i = 0; i < 4; ++i) asm volatile("" : "+v"(hpu[i]));

      f32x4 ar{0,0,0,0}, az{0,0,0,0}, anxh{0,0,0,0}, anxl{0,0,0,0}, anhh{0,0,0,0}, anhl{0,0,0,0};
#pragma unroll
      for (int kc = 0; kc < 32; ++kc) {
        f16x8 wnh = *(const f16x8*)(wlds + (((2*32 + kc)*64 + lane) << 3));
        f16x8 wnl = *(const f16x8*)(wlds + (((3*32 + kc)*64 + lane) << 3));
        ar = __builtin_amdgcn_mfma_f32_16x16x32_f16(afr[kc], wr[kc], ar, 0, 0, 0);
        az = __builtin_amdgcn_mfma_f32_16x16x32_f16(afr[kc], wz[kc], az, 0, 0, 0);
        if (kc < 16) {
          anxh = __builtin_amdgcn_mfma_f32_16x16x32_f16(afr[kc], wnh, anxh, 0, 0, 0);
          anxl = __builtin_amdgcn_mfma_f32_16x16x32_f16(afr[kc], wnl, anxl, 0, 0, 0);
        } else {
          anhh = __builtin_amdgcn_mfma_f32_16x16x32_f16(afr[kc], wnh, anhh, 0, 0, 0);
          anhl = __builtin_amdgcn_mfma_f32_16x16x32_f16(afr[kc], wnl, anhl, 0, 0, 0);
        }
      }
      // epilogue: D layout col(lane&15)=dim j, row(quad*4+i)=batch
      f16* hw = hring + ((size_t)(l*DRING + slot_w)*BATCH)*HID;
#pragma unroll
      for (int i = 0; i < 4; ++i) {
        int bidx = bh*64 + wv*16 + quad*4 + i;
        float rr = sigmoidf_(ar[i] + br);
        float zz = sigmoidf_(az[i] + bz);
        float hn = anhh[i] + anhl[i]*(1.0f/2048.0f) + bn;
        float nn = tanhf_(anxh[i] + anxl[i]*(1.0f/2048.0f) + bin + rr*hn);
        union { unsigned short u; f16 h; } cr; cr.u = (unsigned short)hpu[i];
        float hp = (float)cr.h;
        float hv = nn + zz*(hp - nn);
        union { f16 h; unsigned short u; } cw; cw.h = (f16)hv;
        __hip_atomic_store((unsigned short*)(hw + (size_t)bidx*HID + j), cw.u,
                           __ATOMIC_RELAXED, __HIP_MEMORY_SCOPE_AGENT);
      }
      __builtin_amdgcn_s_waitcnt(0);                  // sc1 stores reached coherence point
      __syncthreads();
      if (tid == 0)
        __hip_atomic_store(F + l*64 + bh*32 + g, t + 1,
                           __ATOMIC_RELAXED, __HIP_MEMORY_SCOPE_AGENT);
    }
  } else if (wg < NLWG + NPWG) {
    const int p = wg - NLWG, bt = p / 5, vt = p % 5, half = bt >> 1;
    __shared__ __align__(16) f16 wolds[8192];
    {
      const f16x8* src = (const f16x8*)((const f16*)(ws + OFF_WOUT) + vt*8192);
      f16x8* dst = (f16x8*)wolds;
      for (int i = tid; i < 1024; i += 256) dst[i] = src[i];
    }
    const int v = vt*16 + nlane;
    const float bo = (v < VOC) ? b_out[v] : 0.0f;
    const int* pollp = F; int pact = 0;
    if (wv == 0 && lane < 32) { pollp = F + 2*64 + half*32 + lane; pact = 1; }
    __syncthreads();
    for (int t = 0; t < T_STEPS; ++t) {
      if (wv == 0) {
        const int tgt = pact ? (t + 1) : NEG_INF_I;
        int spins = 0;
        while (1) {
          int vv = __hip_atomic_load(pollp, __ATOMIC_RELAXED, __HIP_MEMORY_SCOPE_AGENT);
          if (__all(vv >= tgt)) break;
          if (++spins > (1 << 21)) break;
          __builtin_amdgcn_s_sleep(2);
        }
      }
      __syncthreads();
      if (wv < 2) {
        const int bmb = bt*32 + wv*16;
        const f16* hrow = hring + ((size_t)(2*DRING + (t & (DRING-1)))*BATCH + bmb + nlane)*HID + ko;
        f16x8 af[16];
#pragma unroll
        for (int kc = 0; kc < 16; ++kc) af[kc] = ld16_sc(hrow + kc*32);
        asm volatile("s_waitcnt vmcnt(0)" ::: "memory");
#pragma unroll
        for (int kc = 0; kc < 16; ++kc) asm volatile("" : "+v"(af[kc]));
        f32x4 acc{0,0,0,0};
#pragma unroll
        for (int kc = 0; kc < 16; ++kc) {
          f16x8 w = *(const f16x8*)(wolds + ((kc*64 + lane) << 3));
          acc = __builtin_amdgcn_mfma_f32_16x16x32_f16(af[kc], w, acc, 0, 0, 0);
        }
        if (v < VOC) {
#pragma unroll
          for (int i = 0; i < 4; ++i) {
            int bidx = bmb + quad*4 + i;
            out[((size_t)bidx*T_STEPS + t)*VOC + v] = acc[i] + bo;
          }
        }
      }
      __syncthreads();
      if (tid == 0)
        __hip_atomic_store(F + 3*64 + p, t + 1, __ATOMIC_RELAXED, __HIP_MEMORY_SCOPE_AGENT);
    }
  }
}

extern "C" void kernel_launch(void* const* d_in, const int* in_sizes, int n_in,
                              void* d_out, int out_size, void* d_ws, size_t ws_size,
                              hipStream_t stream) {
  const int*   xseq  = (const int*)d_in[0];
  const float* emb   = (const float*)d_in[1];
  const float* w_ih  = (const float*)d_in[2];
  const float* w_hh  = (const float*)d_in[3];
  const float* b     = (const float*)d_in[4];
  const float* b_n   = (const float*)d_in[5];
  const float* w_out = (const float*)d_in[6];
  const float* b_out = (const float*)d_in[7];
  char* ws = (char*)d_ws;

  // zero flags + h ring (h[-1] = 0 initial state); re-done every call
  hipMemsetAsync(d_ws, 0, OFF_HRING + HRING_BYTES, stream);
  hipLaunchKernelGGL(convert_kernel, dim3(4096), dim3(256), 0, stream,
                     emb, w_ih, w_hh, w_out, ws);
  hipLaunchKernelGGL(rnn_kernel, dim3(NLWG + NPWG), dim3(256), 0, stream,
                     xseq, b, b_n, b_out, (float*)d_out, ws);
}

// Round 6
// 8712.691 us; speedup vs baseline: 2.4281x; 1.1614x over previous
//
#include <hip/hip_runtime.h>

typedef _Float16 f16;
typedef _Float16 f16x8 __attribute__((ext_vector_type(8)));
typedef float f32x4 __attribute__((ext_vector_type(4)));

#define T_STEPS 1024
#define BATCH 128
#define HID 512
#define VOC 65
#define DRING 8
#define NLWG 192              // 3 layers * 32 dim-slices * 2 batch-halves
#define NPWG 20               // 4 b-tiles * 5 v-tiles
#define FPAD 16               // ints per flag (64B line) — kills flag-line contention

// workspace layout (bytes)
#define OFF_READY 0           // padded flags: [(l*64+bh*32+g)*FPAD], proj at [(192+p)*FPAD]
#define OFF_HRING 32768
#define HRING_BYTES (3*DRING*BATCH*HID*2)            // 3,145,728
#define OFF_WPACK (OFF_HRING + HRING_BYTES)          // 3,178,496
#define WPACK_BYTES (3*32*65536*2)                   // 12,582,912
#define OFF_WOUT (OFF_WPACK + WPACK_BYTES)           // 15,761,408
#define WOUT_BYTES (5*16*512*2)                      // 81,920
#define OFF_EMB (OFF_WOUT + WOUT_BYTES)              // 15,843,328

__device__ __forceinline__ float sigmoidf_(float x){ return 1.0f/(1.0f+__expf(-x)); }
__device__ __forceinline__ float tanhf_(float x){ return 1.0f - 2.0f/(__expf(2.0f*x)+1.0f); }

// coherent 16B load: bypass L1+L2, read from coherence point (fresh cross-XCD data)
__device__ __forceinline__ f16x8 ld16_sc(const f16* p) {
  f16x8 r;
  asm volatile("global_load_dwordx4 %0, %1, off sc0 sc1" : "=v"(r) : "v"(p) : "memory");
  return r;
}
__device__ __forceinline__ void st16_sc1(f16* p, f16x8 v){
  asm volatile("global_store_dwordx4 %0, %1, off sc1"::"v"(p),"v"(v):"memory"); }

// Pack weights FRAG-MAJOR: per (layer l, slice g): 4 gate-tiles (r, z, n-hi, n-lo*2048)
// x 32 kc x [64 lanes x 8 f16] so a wave's ds_read_b128 is conflict-free.
__global__ void convert_kernel(const float* __restrict__ emb, const float* __restrict__ w_ih,
                               const float* __restrict__ w_hh, const float* __restrict__ w_out,
                               char* __restrict__ ws) {
  f16* wpack = (f16*)(ws + OFF_WPACK);
  f16* wout  = (f16*)(ws + OFF_WOUT);
  f16* embh  = (f16*)(ws + OFF_EMB);
  const int NW = 3*32*65536;
  const int TOT = NW + 40960 + VOC*HID;
  for (int e = blockIdx.x*blockDim.x + threadIdx.x; e < TOT; e += gridDim.x*blockDim.x) {
    if (e < NW) {
      int l = e >> 21, rem = e & 0x1FFFFF;
      int g = rem >> 16, idx = rem & 0xFFFF;
      int gt = idx >> 14, kc = (idx >> 9) & 31, lane = (idx >> 3) & 63, jj = idx & 7;
      int n = lane & 15, q = lane >> 4;
      int k = kc*32 + q*8 + jj, d = g*16 + n;
      int row = (gt==0) ? d : (gt==1) ? 512+d : 1024+d;
      float f = (k < 512) ? w_ih[((size_t)(l*1536+row)<<9) + k]
                          : w_hh[((size_t)(l*1536+row)<<9) + (k-512)];
      f16 h;
      if (gt < 3) h = (f16)f;
      else { f16 hi = (f16)f; h = (f16)((f - (float)hi)*2048.0f); }
      wpack[e] = h;
    } else if (e < NW + 40960) {
      int idx = e - NW;
      int vt = idx >> 13, r2 = idx & 8191;
      int kc = r2 >> 9, lane = (r2 >> 3) & 63, jj = r2 & 7;
      int n = lane & 15, q = lane >> 4;
      int v = vt*16 + n, k = kc*32 + q*8 + jj;
      wout[idx] = (v < VOC) ? (f16)w_out[((size_t)v<<9) + k] : (f16)0.0f;
    } else {
      int idx = e - NW - 40960;
      embh[idx] = (f16)emb[idx];
    }
  }
}

// Persistent kernel, 212 WGs x 256 threads — the proven round-2 protocol with:
//  * 64B-padded flags (no flag-line contention)
//  * h_prev kept in registers (no scattered 2B reload)
//  * LDS-transposed epilogue -> 16B h stores (8x fewer store requests)
__global__ void __launch_bounds__(256) rnn_kernel(const int* __restrict__ xseq,
                           const float* __restrict__ bias, const float* __restrict__ bias_n,
                           const float* __restrict__ b_out, float* __restrict__ out,
                           char* __restrict__ ws) {
  int* F = (int*)(ws + OFF_READY);
  f16* hring = (f16*)(ws + OFF_HRING);                // [3][8][128][512]
  const int wg = blockIdx.x;
  const int tid = threadIdx.x;
  const int lane = tid & 63, wv = tid >> 6;
  const int quad = lane >> 4, ko = quad*8, nlane = lane & 15;

  __shared__ __align__(16) f16 wlds[65536];           // 131,072 B
  __shared__ __align__(16) f16 wolds[8192];           // 16,384 B
  __shared__ __align__(16) f16 hstage[64*24];         // 3,072 B (stride 24 f16 = 48B, 16B-aligned rows)

  if (wg < NLWG) {
    const int l = wg / 64, r = wg % 64, g = r >> 1, bh = r & 1;
    {
      const f16x8* src = (const f16x8*)((const f16*)(ws + OFF_WPACK) + ((size_t)(l*32+g) << 16));
      f16x8* dst = (f16x8*)wlds;
      for (int i = tid; i < 8192; i += 256) dst[i] = src[i];
    }
    const int j = g*16 + nlane;
    const float br  = bias[l*1536 + j];
    const float bz  = bias[l*1536 + 512 + j];
    const float bin = bias[l*1536 + 1024 + j];
    const float bn  = bias_n[l*512 + j];
    const int bm = bh*64 + wv*16 + nlane;             // A-operand batch row

    // per-lane poll assignment: wave0 = self(>=t, lanes 0-31) + prev(>=t+1, lanes 32-63);
    // wave1 = downstream back-pressure (>=t-7)
    const int* pollp = F; int padd = 0; int pact = 0;
    if (wv == 0) {
      if (lane < 32)      { pollp = F + (l*64 + bh*32 + lane)*FPAD;          padd = 0;  pact = 1; }
      else if (l > 0)     { pollp = F + ((l-1)*64 + bh*32 + (lane-32))*FPAD; padd = 1;  pact = 1; }
    } else if (wv == 1) {
      if (l < 2) { if (lane < 32) { pollp = F + ((l+1)*64 + bh*32 + lane)*FPAD; padd = -(DRING-1); pact = 1; } }
      else       { if (lane < 10) { pollp = F + (192 + bh*10 + lane)*FPAD;      padd = -(DRING-1); pact = 1; } }
    }
    __syncthreads();
    // register-resident B-frags for r and z gates; conflict-free reads
    f16x8 wr[32], wz[32];
#pragma unroll
    for (int kc = 0; kc < 32; ++kc) {
      wr[kc] = *(const f16x8*)(wlds + (((0*32 + kc)*64 + lane) << 3));
      wz[kc] = *(const f16x8*)(wlds + (((1*32 + kc)*64 + lane) << 3));
    }
    const f16* embh = (const f16*)(ws + OFF_EMB);
    unsigned short hprev[4] = {0, 0, 0, 0};           // h(t-1) for this thread's (row, col) — f16 bits

    for (int t = 0; t < T_STEPS; ++t) {
      if (wv < 2) {
        const int tgt = t + padd;
        int spins = 0;
        while (1) {
          int v = 0x7FFFFFFF;
          if (pact) v = __hip_atomic_load(pollp, __ATOMIC_RELAXED, __HIP_MEMORY_SCOPE_AGENT);
          if (__all(v >= tgt)) break;
          if (++spins > (1 << 22)) break;             // hang-safety: fail visibly, not forever
          __builtin_amdgcn_s_sleep(1);
        }
      }
      __syncthreads();

      const int slot_w = t & (DRING-1), slot_r = (t + DRING - 1) & (DRING-1);
      f16x8 afr[32];
      if (l == 0) {
        int idx = xseq[bm*T_STEPS + t];
        const f16* xr = embh + (size_t)idx*HID + ko;  // immutable: plain cached loads
#pragma unroll
        for (int kc = 0; kc < 16; ++kc) afr[kc] = *(const f16x8*)(xr + kc*32);
      } else {
        const f16* xr = hring + ((size_t)((l-1)*DRING + slot_w)*BATCH + bm)*HID + ko;
#pragma unroll
        for (int kc = 0; kc < 16; ++kc) afr[kc] = ld16_sc(xr + kc*32);
      }
      {
        const f16* hrk = hring + ((size_t)(l*DRING + slot_r)*BATCH + bm)*HID + ko;
#pragma unroll
        for (int kc = 0; kc < 16; ++kc) afr[16 + kc] = ld16_sc(hrk + kc*32);
      }
      asm volatile("s_waitcnt vmcnt(0)" ::: "memory");
#pragma unroll
      for (int kc = 0; kc < 32; ++kc) asm volatile("" : "+v"(afr[kc]));

      f32x4 ar{0,0,0,0}, az{0,0,0,0}, anxh{0,0,0,0}, anxl{0,0,0,0}, anhh{0,0,0,0}, anhl{0,0,0,0};
#pragma unroll
      for (int kc = 0; kc < 32; ++kc) {
        f16x8 wnh = *(const f16x8*)(wlds + (((2*32 + kc)*64 + lane) << 3));
        f16x8 wnl = *(const f16x8*)(wlds + (((3*32 + kc)*64 + lane) << 3));
        ar = __builtin_amdgcn_mfma_f32_16x16x32_f16(afr[kc], wr[kc], ar, 0, 0, 0);
        az = __builtin_amdgcn_mfma_f32_16x16x32_f16(afr[kc], wz[kc], az, 0, 0, 0);
        if (kc < 16) {
          anxh = __builtin_amdgcn_mfma_f32_16x16x32_f16(afr[kc], wnh, anxh, 0, 0, 0);
          anxl = __builtin_amdgcn_mfma_f32_16x16x32_f16(afr[kc], wnl, anxl, 0, 0, 0);
        } else {
          anhh = __builtin_amdgcn_mfma_f32_16x16x32_f16(afr[kc], wnh, anhh, 0, 0, 0);
          anhl = __builtin_amdgcn_mfma_f32_16x16x32_f16(afr[kc], wnl, anhl, 0, 0, 0);
        }
      }
      // epilogue: D layout col(lane&15)=dim j, row_local(wv*16+quad*4+i)=batch (within bh half)
#pragma unroll
      for (int i = 0; i < 4; ++i) {
        float rr = sigmoidf_(ar[i] + br);
        float zz = sigmoidf_(az[i] + bz);
        float hn = anhh[i] + anhl[i]*(1.0f/2048.0f) + bn;
        float nn = tanhf_(anxh[i] + anxl[i]*(1.0f/2048.0f) + bin + rr*hn);
        union { unsigned short u; f16 h; } cr; cr.u = hprev[i];
        float hv = nn + zz*((float)cr.h - nn);
        union { f16 h; unsigned short u; } cw; cw.h = (f16)hv;
        hprev[i] = cw.u;
        hstage[(wv*16 + quad*4 + i)*24 + nlane] = cw.h;   // LDS transpose stage
      }
      __syncthreads();
      // coalesced 16B h stores: 128 threads, one 16B chunk each (row, 8 cols)
      if (tid < 128) {
        int row = tid >> 1, half = tid & 1;
        f16x8 v8 = *(const f16x8*)(hstage + row*24 + half*8);
        f16* hw = hring + ((size_t)(l*DRING + slot_w)*BATCH + bh*64 + row)*HID + g*16 + half*8;
        st16_sc1(hw, v8);
      }
      asm volatile("s_waitcnt vmcnt(0)" ::: "memory"); // sc1 stores reached coherence point
      __syncthreads();
      if (tid == 0)
        __hip_atomic_store(F + (l*64 + bh*32 + g)*FPAD, t + 1,
                           __ATOMIC_RELAXED, __HIP_MEMORY_SCOPE_AGENT);
    }
  } else if (wg < NLWG + NPWG) {
    const int p = wg - NLWG, bt = p / 5, vt = p % 5, half = bt >> 1;
    {
      const f16x8* src = (const f16x8*)((const f16*)(ws + OFF_WOUT) + vt*8192);
      f16x8* dst = (f16x8*)wolds;
      for (int i = tid; i < 1024; i += 256) dst[i] = src[i];
    }
    const int v = vt*16 + nlane;
    const float bo = (v < VOC) ? b_out[v] : 0.0f;
    __syncthreads();
    for (int t = 0; t < T_STEPS; ++t) {
      if (wv == 0) {
        const int tgt = t + 1;
        int spins = 0;
        while (1) {
          int vv = 0x7FFFFFFF;
          if (lane < 32) vv = __hip_atomic_load(F + (2*64 + half*32 + lane)*FPAD,
                                                __ATOMIC_RELAXED, __HIP_MEMORY_SCOPE_AGENT);
          if (__all(vv >= tgt)) break;
          if (++spins > (1 << 22)) break;
          __builtin_amdgcn_s_sleep(1);
        }
      }
      __syncthreads();
      if (wv < 2) {
        const int bmb = bt*32 + wv*16;
        const f16* hrow = hring + ((size_t)(2*DRING + (t & (DRING-1)))*BATCH + bmb + nlane)*HID + ko;
        f16x8 af[16];
#pragma unroll
        for (int kc = 0; kc < 16; ++kc) af[kc] = ld16_sc(hrow + kc*32);
        asm volatile("s_waitcnt vmcnt(0)" ::: "memory");
#pragma unroll
        for (int kc = 0; kc < 16; ++kc) asm volatile("" : "+v"(af[kc]));
        f32x4 acc{0,0,0,0};
#pragma unroll
        for (int kc = 0; kc < 16; ++kc) {
          f16x8 w = *(const f16x8*)(wolds + ((kc*64 + lane) << 3));
          acc = __builtin_amdgcn_mfma_f32_16x16x32_f16(af[kc], w, acc, 0, 0, 0);
        }
        if (v < VOC) {
#pragma unroll
          for (int i = 0; i < 4; ++i) {
            int bidx = bmb + quad*4 + i;
            out[((size_t)bidx*T_STEPS + t)*VOC + v] = acc[i] + bo;
          }
        }
      }
      __syncthreads();
      if (tid == 0)
        __hip_atomic_store(F + (192 + p)*FPAD, t + 1, __ATOMIC_RELAXED, __HIP_MEMORY_SCOPE_AGENT);
    }
  }
}

extern "C" void kernel_launch(void* const* d_in, const int* in_sizes, int n_in,
                              void* d_out, int out_size, void* d_ws, size_t ws_size,
                              hipStream_t stream) {
  const int*   xseq  = (const int*)d_in[0];
  const float* emb   = (const float*)d_in[1];
  const float* w_ih  = (const float*)d_in[2];
  const float* w_hh  = (const float*)d_in[3];
  const float* b     = (const float*)d_in[4];
  const float* b_n   = (const float*)d_in[5];
  const float* w_out = (const float*)d_in[6];
  const float* b_out = (const float*)d_in[7];
  char* ws = (char*)d_ws;

  // zero flags + h ring (h[-1] = 0 initial state); re-done every call
  (void)hipMemsetAsync(d_ws, 0, OFF_HRING + HRING_BYTES, stream);
  hipLaunchKernelGGL(convert_kernel, dim3(4096), dim3(256), 0, stream,
                     emb, w_ih, w_hh, w_out, ws);
  hipLaunchKernelGGL(rnn_kernel, dim3(NLWG + NPWG), dim3(256), 0, stream,
                     xseq, b, b_n, b_out, (float*)d_out, ws);
}